// Round 13
// baseline (498.360 us; speedup 1.0000x reference)
//
#include <hip/hip_runtime.h>
#include <math.h>

// FlowLayer: 2 steps of manifold (S^2) graph heat flow.
// N=50000 nodes, C=16 channels, D=3, E=1.6M edges.
//
// Build (no global atomics): LDS-privatized histogram (R12), 3-phase scan,
// atomic-free fill packing (w, rcv*16) + 32 zero sentinels.
//
// Flow (R13): XCD channel-group affinity. x padded [N][16] float4; channels
// split into 4 groups of 4; block's group = blockIdx&3 which, under the
// round-robin blockIdx->XCD mapping (b%8), pins each XCD to ONE group ->
// 3.2MB gather slice fits the 4MiB per-XCD L2 (R11 measured: full 12.8MB
// footprint misses L2, 172-253MB LLC traffic/step). Wave = 1 node x
// (16 slots x 4 channels); 200K waves for latency hiding (R8 lesson).
// q gather = one dwordx4; pair stream nt-tagged (read 4x, keep L2 for x).
//
// NOTE: |u|^2 MUST be computed from u's components (not 1-cs^2): near
// antipodal pairs 1-cs^2 cancels catastrophically -> rsq explodes (R5 bug).

constexpr float EPS64F = 2.2204460492503131e-16f;  // np.float64 eps
constexpr float PI_F   = 3.14159265358979323846f;
constexpr int   SR_BITS = 14;                 // 16384-node subranges (64KB LDS)
constexpr int   CH_BITS = 15;                 // 32768-edge chunks

typedef int   vi4 __attribute__((ext_vector_type(4)));
typedef float vf4 __attribute__((ext_vector_type(4)));
typedef float vf2 __attribute__((ext_vector_type(2)));

// ---------------- CSR build ----------------

__global__ __launch_bounds__(256) void lhist_kernel(
    const int* __restrict__ snd, unsigned char* __restrict__ pos,
    int* __restrict__ partial2, int E, int NC) {
  __shared__ int h[1 << SR_BITS];
  int tid = threadIdx.x;
  int c = blockIdx.x, s = blockIdx.y;
  for (int i = tid; i < (1 << SR_BITS); i += 256) h[i] = 0;
  __syncthreads();
  int base = c << CH_BITS;
  int cnt = min(1 << CH_BITS, E - base);
  int s0 = s << SR_BITS;
  const vi4* snd4 = (const vi4*)(snd + base);  // base is 32768-aligned
  int cnt4 = cnt >> 2;
  for (int i = tid; i < cnt4; i += 256) {
    vi4 sv = snd4[i];
    int e = base + (i << 2);
    int v;
    v = sv.x - s0; if ((unsigned)v < (1u << SR_BITS)) pos[e]     = (unsigned char)atomicAdd(&h[v], 1);
    v = sv.y - s0; if ((unsigned)v < (1u << SR_BITS)) pos[e + 1] = (unsigned char)atomicAdd(&h[v], 1);
    v = sv.z - s0; if ((unsigned)v < (1u << SR_BITS)) pos[e + 2] = (unsigned char)atomicAdd(&h[v], 1);
    v = sv.w - s0; if ((unsigned)v < (1u << SR_BITS)) pos[e + 3] = (unsigned char)atomicAdd(&h[v], 1);
  }
  if (tid == 0) {  // chunk tail (cnt % 4)
    for (int i = cnt4 << 2; i < cnt; ++i) {
      int v = snd[base + i] - s0;
      if ((unsigned)v < (1u << SR_BITS))
        pos[base + i] = (unsigned char)atomicAdd(&h[v], 1);
    }
  }
  __syncthreads();
  int* dst = partial2 + ((size_t)(s * NC + c) << SR_BITS);
  for (int i = tid; i < (1 << SR_BITS); i += 256) dst[i] = h[i];
}

__global__ __launch_bounds__(256) void scan1_kernel(
    const int* __restrict__ partial2, int* __restrict__ boff,
    int* __restrict__ tot, int N, int NC) {
  int v = blockIdx.x * 256 + threadIdx.x;
  if (v >= N) return;
  int s = v >> SR_BITS, lv = v & ((1 << SR_BITS) - 1);
  int run = 0;
  for (int c = 0; c < NC; ++c) {
    int t = partial2[((size_t)(s * NC + c) << SR_BITS) + lv];
    boff[(size_t)c * N + v] = run;
    run += t;
  }
  tot[v] = run;
}

__global__ __launch_bounds__(1024) void scanA_kernel(
    const int* __restrict__ tot, int* __restrict__ row_start,
    int* __restrict__ btot, int N) {
  __shared__ int wsum[16];
  int tid = threadIdx.x;
  int lane = tid & 63, wave = tid >> 6;
  int i = blockIdx.x * 1024 + tid;
  int v = (i < N) ? tot[i] : 0;
  int incl = v;
  #pragma unroll
  for (int off = 1; off < 64; off <<= 1) {
    int t = __shfl_up(incl, off, 64);
    if (lane >= off) incl += t;
  }
  if (lane == 63) wsum[wave] = incl;
  __syncthreads();
  if (wave == 0 && lane < 16) {
    int wincl = wsum[lane];
    #pragma unroll
    for (int off = 1; off < 16; off <<= 1) {
      int t = __shfl_up(wincl, off, 64);
      if (lane >= off) wincl += t;
    }
    wsum[lane] = wincl;
  }
  __syncthreads();
  int woff = (wave > 0) ? wsum[wave - 1] : 0;
  if (i < N) row_start[i] = woff + incl - v;
  if (tid == 0) btot[blockIdx.x] = wsum[15];
}

__global__ __launch_bounds__(64) void scanB_kernel(
    const int* __restrict__ btot, int* __restrict__ boffb,
    int* __restrict__ row_start, int nb, int N) {
  int lane = threadIdx.x;
  int v = (lane < nb) ? btot[lane] : 0;
  int incl = v;
  #pragma unroll
  for (int off = 1; off < 64; off <<= 1) {
    int t = __shfl_up(incl, off, 64);
    if (lane >= off) incl += t;
  }
  if (lane < nb) boffb[lane] = incl - v;
  if (lane == 63) row_start[N] = incl;  // grand total
}

__global__ __launch_bounds__(1024) void scanC_kernel(
    int* __restrict__ row_start, const int* __restrict__ boffb, int N) {
  int i = blockIdx.x * 1024 + threadIdx.x;
  if (i < N) row_start[i] += boffb[blockIdx.x];
}

__global__ __launch_bounds__(256) void scanD_kernel(
    int* __restrict__ boff, const int* __restrict__ row_start, int N, int NC) {
  int v = blockIdx.x * 256 + threadIdx.x;
  if (v >= N) return;
  int rs = row_start[v];
  for (int c = 0; c < NC; ++c) boff[(size_t)c * N + v] += rs;
}

// Atomic-free fill: slot = boff[chunk][snd] + pos[e]; packs (w, rcv*16);
// 32 zero sentinels past pair[E].
__global__ __launch_bounds__(256) void fill_kernel(
    const vi4* __restrict__ snd4, const vi4* __restrict__ rcv4,
    const vf4* __restrict__ ew4, const unsigned char* __restrict__ pos,
    const int* __restrict__ boff, long long* __restrict__ pair,
    const int* __restrict__ snd, const int* __restrict__ rcv,
    const float* __restrict__ ew, int N, int E) {
  int tid = threadIdx.x;
  int E4 = E >> 2;
  #pragma unroll
  for (int gg = 0; gg < 2; ++gg) {
    int g = blockIdx.x * 512 + gg * 256 + tid;
    if (g < E4) {
      int e = g << 2;
      const int* bc = boff + (size_t)(e >> CH_BITS) * N;  // same chunk e..e+3
      vi4 s = __builtin_nontemporal_load(&snd4[g]);
      vi4 r = __builtin_nontemporal_load(&rcv4[g]);
      vf4 w = __builtin_nontemporal_load(&ew4[g]);
      unsigned pb = *(const unsigned*)(pos + e);
      pair[bc[s.x] + (pb & 255u)] =
          (long long)(((unsigned long long)(unsigned)__float_as_int(w.x) << 32) | (unsigned)(r.x * 16));
      pair[bc[s.y] + ((pb >> 8) & 255u)] =
          (long long)(((unsigned long long)(unsigned)__float_as_int(w.y) << 32) | (unsigned)(r.y * 16));
      pair[bc[s.z] + ((pb >> 16) & 255u)] =
          (long long)(((unsigned long long)(unsigned)__float_as_int(w.z) << 32) | (unsigned)(r.z * 16));
      pair[bc[s.w] + (pb >> 24)] =
          (long long)(((unsigned long long)(unsigned)__float_as_int(w.w) << 32) | (unsigned)(r.w * 16));
    }
  }
  if (blockIdx.x == 0 && tid == 0) {
    for (int e = E4 << 2; e < E; ++e) {  // edge tail
      pair[boff[(size_t)(e >> CH_BITS) * N + snd[e]] + pos[e]] =
          (long long)(((unsigned long long)(unsigned)__float_as_int(ew[e]) << 32) | (unsigned)(rcv[e] * 16));
    }
    for (int z = 0; z < 32; ++z) pair[(size_t)E + z] = 0;  // sentinels (w=0)
  }
}

// nodes [N][48] -> xp [N*16] float4 (pad 4th comp). t = n*16+c.
__global__ __launch_bounds__(256) void conv_kernel(
    const float* __restrict__ xf, vf4* __restrict__ xp, int NC16) {
  int t = blockIdx.x * 256 + threadIdx.x;
  if (t >= NC16) return;
  vf4 v;
  v.x = xf[t * 3]; v.y = xf[t * 3 + 1]; v.z = xf[t * 3 + 2]; v.w = 0.f;
  xp[t] = v;
}

// ---------------- flow ----------------

__device__ __forceinline__ void edge_accum_pk(
    vf2 p0, vf2 p1, vf2 p2, vf2 q0, vf2 q1, vf2 q2, vf2 w,
    vf2& a0, vf2& a1, vf2& a2) {
  vf2 cs = p0 * q0 + p1 * q1 + p2 * q2;
  cs = __builtin_elementwise_min(vf2{1.f, 1.f},
       __builtin_elementwise_max(vf2{-1.f, -1.f}, cs));
  vf2 u0 = q0 - cs * p0;
  vf2 u1 = q1 - cs * p1;
  vf2 u2 = q2 - cs * p2;
  vf2 un2 = __builtin_elementwise_max(u0 * u0 + u1 * u1 + u2 * u2,
                                      vf2{1e-24f, 1e-24f});
  vf2 ax = __builtin_elementwise_abs(cs);
  vf2 s = __builtin_elementwise_sqrt(vf2{1.f, 1.f} - ax);
  vf2 poly = ((ax * -0.0187293f + 0.0742610f) * ax - 0.2121144f) * ax
             + 1.5707288f;
  vf2 th = s * poly;
  vf2 theta;
  theta.x = (cs.x >= 0.0f) ? th.x : (PI_F - th.x);
  theta.y = (cs.y >= 0.0f) ? th.y : (PI_F - th.y);
  vf2 rsq;
  rsq.x = __builtin_amdgcn_rsqf(un2.x);
  rsq.y = __builtin_amdgcn_rsqf(un2.y);
  vf2 coef = w * theta * rsq;
  a0 += coef * u0;
  a1 += coef * u1;
  a2 += coef * u2;
}

__device__ __forceinline__ void node_step(
    float a0, float a1, float a2, float ws, float p0, float p1, float p2,
    float ts, float dsv, float& y0, float& y1, float& y2) {
  // v_lap = -agg/deg; nrm/scale sign-invariant; -(v_lap*scale)*t = +g*scale*t
  float invdg = __builtin_amdgcn_rcpf(ws + 1e-12f);
  float g0 = a0 * invdg, g1 = a1 * invdg, g2 = a2 * invdg;
  float nrm = sqrtf(fmaf(g0, g0, fmaf(g1, g1, g2 * g2)) + EPS64F);
  float tch = ts * ts * 0.5f;  // t_sqrt^2 / N_STEPS
  float dch = dsv * dsv;
  float alp = __builtin_amdgcn_rcpf(1.0f + __expf(dch - nrm));  // sigmoid
  float scale = (nrm * alp <= 1.0f) ? alp : __builtin_amdgcn_rcpf(nrm);
  float f = scale * tch;
  float v0 = g0 * f, v1 = g1 * f, v2 = g2 * f;
  float nv = sqrtf(fmaf(v0, v0, fmaf(v1, v1, v2 * v2)));
  float cn = __cosf(nv);
  float sc = (nv > 1e-20f) ? (__sinf(nv) * __builtin_amdgcn_rcpf(nv)) : 1.0f;
  float t0 = fmaf(cn, p0, sc * v0);
  float t1 = fmaf(cn, p1, sc * v1);
  float t2 = fmaf(cn, p2, sc * v2);
  float inv = __builtin_amdgcn_rsqf(fmaf(t0, t0, fmaf(t1, t1, t2 * t2)));
  y0 = t0 * inv; y1 = t1 * inv; y2 = t2 * inv;
}

// XCD channel-group flow. block b: group g = b&3 (aligns with XCD = b%8),
// nodes (b>>2)*4 + wave. lane = k*4 + cl: edge slot k in [0,16), channel
// c = g*4+cl. 32 edges per wave-iter (16 slots x 2 packed).
// out48 != null => final unpadded write; else padded yp.
__global__ __launch_bounds__(256) void flowx_kernel(
    const vf4* __restrict__ xp, const int* __restrict__ row_start,
    const long long* __restrict__ pair, const float* __restrict__ tsq,
    const float* __restrict__ dsq, vf4* __restrict__ yp,
    float* __restrict__ out48, int N) {
  int b = blockIdx.x;
  int g = b & 3;
  int node = (b >> 2) * 4 + (threadIdx.x >> 6);
  if (node >= N) return;
  int lane = threadIdx.x & 63;
  int c = g * 4 + (lane & 3);
  int k = lane >> 2;
  int beg = row_start[node];
  int end = row_start[node + 1];
  vf4 p = xp[node * 16 + c];
  vf2 p0 = {p.x, p.x}, p1 = {p.y, p.y}, p2 = {p.z, p.z};
  vf2 a0 = {0.f, 0.f}, a1 = {0.f, 0.f}, a2 = {0.f, 0.f}, wsv = {0.f, 0.f};
  int iters = (end - beg + 31) >> 5;
  int j = beg + k;
  for (int t = 0; t < iters; ++t, j += 32) {
    long long e0 = __builtin_nontemporal_load(&pair[j]);
    long long e1 = __builtin_nontemporal_load(&pair[j + 16]);
    float w0 = (j      < end) ? __int_as_float((int)(e0 >> 32)) : 0.f;
    float w1 = (j + 16 < end) ? __int_as_float((int)(e1 >> 32)) : 0.f;
    vf4 qa = xp[(int)e0 + c];
    vf4 qb = xp[(int)e1 + c];
    vf2 w = {w0, w1};
    edge_accum_pk(p0, p1, p2, vf2{qa.x, qb.x}, vf2{qa.y, qb.y},
                  vf2{qa.z, qb.z}, w, a0, a1, a2);
    wsv += w;
  }
  float A0 = a0.x + a0.y, A1 = a1.x + a1.y, A2 = a2.x + a2.y;
  float ws = wsv.x + wsv.y;
  // reduce over k (lane bits 2..5)
  A0 += __shfl_xor(A0, 4);  A1 += __shfl_xor(A1, 4);
  A2 += __shfl_xor(A2, 4);  ws += __shfl_xor(ws, 4);
  A0 += __shfl_xor(A0, 8);  A1 += __shfl_xor(A1, 8);
  A2 += __shfl_xor(A2, 8);  ws += __shfl_xor(ws, 8);
  A0 += __shfl_xor(A0, 16); A1 += __shfl_xor(A1, 16);
  A2 += __shfl_xor(A2, 16); ws += __shfl_xor(ws, 16);
  A0 += __shfl_xor(A0, 32); A1 += __shfl_xor(A1, 32);
  A2 += __shfl_xor(A2, 32); ws += __shfl_xor(ws, 32);
  if (k == 0) {
    float y0, y1, y2;
    node_step(A0, A1, A2, ws, p.x, p.y, p.z, tsq[c], dsq[c], y0, y1, y2);
    if (out48) {
      int ip = node * 48 + c * 3;
      out48[ip] = y0; out48[ip + 1] = y1; out48[ip + 2] = y2;
    } else {
      vf4 v; v.x = y0; v.y = y1; v.z = y2; v.w = 0.f;
      yp[node * 16 + c] = v;
    }
  }
}

static inline size_t al16(size_t x) { return (x + 15) & ~(size_t)15; }

extern "C" void kernel_launch(void* const* d_in, const int* in_sizes, int n_in,
                              void* d_out, int out_size, void* d_ws, size_t ws_size,
                              hipStream_t stream) {
  const float* nodes = (const float*)d_in[0];  // [N,16,3]
  const float* ew    = (const float*)d_in[1];  // [E]
  const float* tsq   = (const float*)d_in[2];  // [16]
  const float* dsq   = (const float*)d_in[3];  // [16]
  const int*   snd   = (const int*)d_in[4];    // [E]
  const int*   rcv   = (const int*)d_in[5];    // [E]
  float* out = (float*)d_out;

  int E = in_sizes[1];
  int N = in_sizes[0] / 48;

  int NS = (N + (1 << SR_BITS) - 1) >> SR_BITS;  // node subranges
  int NC = (E + (1 << CH_BITS) - 1) >> CH_BITS;  // edge chunks

  // workspace (~50MB): row_start | aux | pair[E+32] | partial2 | boff | tot
  // | pos[E bytes] | xp0[N*16 f4]   ; xtmp (padded intermediate) aliases
  // partial2 (dead after scan1; 12.85MB >= 12.8MB needed).
  size_t rsB   = al16((size_t)(N + 4) * 4);
  size_t auxB  = 512;
  size_t pairB = al16((size_t)(E + 32) * 8);
  size_t p2B   = al16(((size_t)NS * NC << SR_BITS) * 4);
  size_t boffB = al16((size_t)NC * N * 4);
  size_t totB  = al16((size_t)N * 4);
  size_t posB  = al16((size_t)E);

  char* base = (char*)d_ws;
  int*           row_start = (int*)base;
  int*           btot      = (int*)(base + rsB);
  int*           boffb     = btot + 64;
  long long*     pair      = (long long*)(base + rsB + auxB);
  int*           partial2  = (int*)(base + rsB + auxB + pairB);
  int*           boff      = (int*)(base + rsB + auxB + pairB + p2B);
  int*           tot       = (int*)(base + rsB + auxB + pairB + p2B + boffB);
  unsigned char* pos       = (unsigned char*)(base + rsB + auxB + pairB + p2B + boffB + totB);
  vf4*           xp0       = (vf4*)(base + rsB + auxB + pairB + p2B + boffB + totB + posB);
  vf4*           xtmp      = (vf4*)partial2;  // aliased; dead after scan1

  int E4  = E >> 2;
  int nb  = (N + 1023) / 1024;
  int nb2 = (N + 255) / 256;
  int fbk = (E4 + 511) / 512;
  int cb  = (N * 16 + 255) / 256;
  int gb  = ((N + 3) / 4) * 4;  // node-quads x 4 channel groups

  conv_kernel<<<cb, 256, 0, stream>>>(nodes, xp0, N * 16);
  lhist_kernel<<<dim3(NC, NS), 256, 0, stream>>>(snd, pos, partial2, E, NC);
  scan1_kernel<<<nb2, 256, 0, stream>>>(partial2, boff, tot, N, NC);
  scanA_kernel<<<nb, 1024, 0, stream>>>(tot, row_start, btot, N);
  scanB_kernel<<<1, 64, 0, stream>>>(btot, boffb, row_start, nb, N);
  scanC_kernel<<<nb, 1024, 0, stream>>>(row_start, boffb, N);
  scanD_kernel<<<nb2, 256, 0, stream>>>(boff, row_start, N, NC);
  fill_kernel<<<fbk, 256, 0, stream>>>((const vi4*)snd, (const vi4*)rcv,
                                       (const vf4*)ew, pos, boff, pair,
                                       snd, rcv, ew, N, E);

  // step 1: xp0 -> xtmp (padded); step 2: xtmp -> out (unpadded write)
  flowx_kernel<<<gb, 256, 0, stream>>>(xp0, row_start, pair, tsq, dsq,
                                       xtmp, (float*)0, N);
  flowx_kernel<<<gb, 256, 0, stream>>>(xtmp, row_start, pair, tsq, dsq,
                                       (vf4*)0, out, N);
}

// Round 14
// 306.316 us; speedup vs baseline: 1.6269x; 1.6269x over previous
//
#include <hip/hip_runtime.h>
#include <math.h>

// FlowLayer: 2 steps of manifold (S^2) graph heat flow.
// N=50000 nodes, C=16 channels, D=3, E=1.6M edges.
//
// Build (no global atomics): LDS-privatized histogram (R12), 3-phase scan
// (scanC+D fused), atomic-free fill packing (w, rcv*64) + 32 zero sentinels.
//
// Flow: established (R10-R13): dur ~= FETCH / ~3 TB/s (L2-miss random-line
// ceiling); line utilization already 100%. Lever = bytes/row: fp16 copy
// xh [N][16][4] halves (128B rows, 6.4MB vs 9.6MB fp32). One dwordx2 per
// edge-channel gather, pair premult rcv*64, pk-float2 math. Guard (R5/R9):
// un2_raw < 1e-4 && w>0 -> rare fp32 refetch (bounds direction noise near
// antipodal). Step1 writes fp32+fp16; step2 writes fp32 out.
//
// NOTE: |u|^2 MUST be computed from u's components (not 1-cs^2): near
// antipodal pairs 1-cs^2 cancels catastrophically -> rsq explodes (R5 bug).

constexpr float EPS64F = 2.2204460492503131e-16f;  // np.float64 eps
constexpr float PI_F   = 3.14159265358979323846f;
constexpr int   SR_BITS = 14;                 // 16384-node subranges (64KB LDS)
constexpr int   CH_BITS = 15;                 // 32768-edge chunks

typedef int      vi4 __attribute__((ext_vector_type(4)));
typedef float    vf4 __attribute__((ext_vector_type(4)));
typedef float    vf2 __attribute__((ext_vector_type(2)));
typedef _Float16 vh4 __attribute__((ext_vector_type(4)));

// ---------------- CSR build ----------------

__global__ __launch_bounds__(256) void lhist_kernel(
    const int* __restrict__ snd, unsigned char* __restrict__ pos,
    int* __restrict__ partial2, int E, int NC) {
  __shared__ int h[1 << SR_BITS];
  int tid = threadIdx.x;
  int c = blockIdx.x, s = blockIdx.y;
  for (int i = tid; i < (1 << SR_BITS); i += 256) h[i] = 0;
  __syncthreads();
  int base = c << CH_BITS;
  int cnt = min(1 << CH_BITS, E - base);
  int s0 = s << SR_BITS;
  const vi4* snd4 = (const vi4*)(snd + base);  // base is 32768-aligned
  int cnt4 = cnt >> 2;
  for (int i = tid; i < cnt4; i += 256) {
    vi4 sv = snd4[i];
    int e = base + (i << 2);
    int v;
    v = sv.x - s0; if ((unsigned)v < (1u << SR_BITS)) pos[e]     = (unsigned char)atomicAdd(&h[v], 1);
    v = sv.y - s0; if ((unsigned)v < (1u << SR_BITS)) pos[e + 1] = (unsigned char)atomicAdd(&h[v], 1);
    v = sv.z - s0; if ((unsigned)v < (1u << SR_BITS)) pos[e + 2] = (unsigned char)atomicAdd(&h[v], 1);
    v = sv.w - s0; if ((unsigned)v < (1u << SR_BITS)) pos[e + 3] = (unsigned char)atomicAdd(&h[v], 1);
  }
  if (tid == 0) {  // chunk tail (cnt % 4)
    for (int i = cnt4 << 2; i < cnt; ++i) {
      int v = snd[base + i] - s0;
      if ((unsigned)v < (1u << SR_BITS))
        pos[base + i] = (unsigned char)atomicAdd(&h[v], 1);
    }
  }
  __syncthreads();
  int* dst = partial2 + ((size_t)(s * NC + c) << SR_BITS);
  for (int i = tid; i < (1 << SR_BITS); i += 256) dst[i] = h[i];
}

__global__ __launch_bounds__(256) void scan1_kernel(
    const int* __restrict__ partial2, int* __restrict__ boff,
    int* __restrict__ tot, int N, int NC) {
  int v = blockIdx.x * 256 + threadIdx.x;
  if (v >= N) return;
  int s = v >> SR_BITS, lv = v & ((1 << SR_BITS) - 1);
  int run = 0;
  for (int c = 0; c < NC; ++c) {
    int t = partial2[((size_t)(s * NC + c) << SR_BITS) + lv];
    boff[(size_t)c * N + v] = run;
    run += t;
  }
  tot[v] = run;
}

__global__ __launch_bounds__(1024) void scanA_kernel(
    const int* __restrict__ tot, int* __restrict__ row_start,
    int* __restrict__ btot, int N) {
  __shared__ int wsum[16];
  int tid = threadIdx.x;
  int lane = tid & 63, wave = tid >> 6;
  int i = blockIdx.x * 1024 + tid;
  int v = (i < N) ? tot[i] : 0;
  int incl = v;
  #pragma unroll
  for (int off = 1; off < 64; off <<= 1) {
    int t = __shfl_up(incl, off, 64);
    if (lane >= off) incl += t;
  }
  if (lane == 63) wsum[wave] = incl;
  __syncthreads();
  if (wave == 0 && lane < 16) {
    int wincl = wsum[lane];
    #pragma unroll
    for (int off = 1; off < 16; off <<= 1) {
      int t = __shfl_up(wincl, off, 64);
      if (lane >= off) wincl += t;
    }
    wsum[lane] = wincl;
  }
  __syncthreads();
  int woff = (wave > 0) ? wsum[wave - 1] : 0;
  if (i < N) row_start[i] = woff + incl - v;
  if (tid == 0) btot[blockIdx.x] = wsum[15];
}

__global__ __launch_bounds__(64) void scanB_kernel(
    const int* __restrict__ btot, int* __restrict__ boffb,
    int* __restrict__ row_start, int nb, int N) {
  int lane = threadIdx.x;
  int v = (lane < nb) ? btot[lane] : 0;
  int incl = v;
  #pragma unroll
  for (int off = 1; off < 64; off <<= 1) {
    int t = __shfl_up(incl, off, 64);
    if (lane >= off) incl += t;
  }
  if (lane < nb) boffb[lane] = incl - v;
  if (lane == 63) row_start[N] = incl;  // grand total
}

// Fused scanC+scanD: finalize row_start and push into all chunk bases.
__global__ __launch_bounds__(256) void scanCD_kernel(
    int* __restrict__ row_start, const int* __restrict__ boffb,
    int* __restrict__ boff, int N, int NC) {
  int i = blockIdx.x * 256 + threadIdx.x;
  if (i >= N) return;
  int rs = row_start[i] + boffb[i >> 10];
  row_start[i] = rs;
  for (int c = 0; c < NC; ++c) boff[(size_t)c * N + i] += rs;
}

// Atomic-free fill: slot = boff[chunk][snd] + pos[e]; packs (w, rcv*64);
// 32 zero sentinels past pair[E].
__global__ __launch_bounds__(256) void fill_kernel(
    const vi4* __restrict__ snd4, const vi4* __restrict__ rcv4,
    const vf4* __restrict__ ew4, const unsigned char* __restrict__ pos,
    const int* __restrict__ boff, long long* __restrict__ pair,
    const int* __restrict__ snd, const int* __restrict__ rcv,
    const float* __restrict__ ew, int N, int E) {
  int tid = threadIdx.x;
  int E4 = E >> 2;
  #pragma unroll
  for (int gg = 0; gg < 2; ++gg) {
    int g = blockIdx.x * 512 + gg * 256 + tid;
    if (g < E4) {
      int e = g << 2;
      const int* bc = boff + (size_t)(e >> CH_BITS) * N;  // same chunk e..e+3
      vi4 s = __builtin_nontemporal_load(&snd4[g]);
      vi4 r = __builtin_nontemporal_load(&rcv4[g]);
      vf4 w = __builtin_nontemporal_load(&ew4[g]);
      unsigned pb = *(const unsigned*)(pos + e);
      pair[bc[s.x] + (pb & 255u)] =
          (long long)(((unsigned long long)(unsigned)__float_as_int(w.x) << 32) | (unsigned)(r.x * 64));
      pair[bc[s.y] + ((pb >> 8) & 255u)] =
          (long long)(((unsigned long long)(unsigned)__float_as_int(w.y) << 32) | (unsigned)(r.y * 64));
      pair[bc[s.z] + ((pb >> 16) & 255u)] =
          (long long)(((unsigned long long)(unsigned)__float_as_int(w.z) << 32) | (unsigned)(r.z * 64));
      pair[bc[s.w] + (pb >> 24)] =
          (long long)(((unsigned long long)(unsigned)__float_as_int(w.w) << 32) | (unsigned)(r.w * 64));
    }
  }
  if (blockIdx.x == 0 && tid == 0) {
    for (int e = E4 << 2; e < E; ++e) {  // edge tail
      pair[boff[(size_t)(e >> CH_BITS) * N + snd[e]] + pos[e]] =
          (long long)(((unsigned long long)(unsigned)__float_as_int(ew[e]) << 32) | (unsigned)(rcv[e] * 64));
    }
    for (int z = 0; z < 32; ++z) pair[(size_t)E + z] = 0;  // sentinels (w=0)
  }
}

// nodes [N][48] fp32 -> xh [N*16] vh4. t = n*16+c.
__global__ __launch_bounds__(256) void conv_kernel(
    const float* __restrict__ xf, _Float16* __restrict__ xh, int NC16) {
  int t = blockIdx.x * 256 + threadIdx.x;
  if (t >= NC16) return;
  vh4 h;
  h.x = (_Float16)xf[t * 3];
  h.y = (_Float16)xf[t * 3 + 1];
  h.z = (_Float16)xf[t * 3 + 2];
  h.w = (_Float16)0.f;
  *(vh4*)(xh + (size_t)t * 4) = h;
}

// ---------------- flow ----------------

// fp32 scalar redo for guard-flagged edges (rare): exact R10 math.
__device__ __forceinline__ void redo32(
    const float* __restrict__ xf, int v64, int c3,
    float P0, float P1, float P2, float w,
    float& d0, float& d1, float& d2) {
  const float* q = xf + ((v64 >> 6) * 48 + c3);
  float q0 = q[0], q1 = q[1], q2 = q[2];
  float cs = fminf(1.0f, fmaxf(-1.0f, fmaf(P0, q0, fmaf(P1, q1, P2 * q2))));
  float u0 = fmaf(-cs, P0, q0);
  float u1 = fmaf(-cs, P1, q1);
  float u2 = fmaf(-cs, P2, q2);
  float un2 = fmaxf(fmaf(u0, u0, fmaf(u1, u1, u2 * u2)), 1e-24f);
  float ax = fabsf(cs);
  float s = sqrtf(1.0f - ax);
  float poly = fmaf(ax, fmaf(ax, fmaf(ax, -0.0187293f, 0.0742610f),
                             -0.2121144f), 1.5707288f);
  float th = s * poly;
  float theta = (cs >= 0.0f) ? th : (PI_F - th);
  float coef = w * theta * __builtin_amdgcn_rsqf(un2);
  d0 = coef * u0; d1 = coef * u1; d2 = coef * u2;
}

// Packed 2-edge accumulate with fp16-noise guard.
__device__ __forceinline__ void edge_accum_pk_g(
    vf2 p0, vf2 p1, vf2 p2, vf2 q0, vf2 q1, vf2 q2, vf2 w,
    int vA, int vB, int c3, const float* __restrict__ xf,
    vf2& a0, vf2& a1, vf2& a2) {
  vf2 cs = p0 * q0 + p1 * q1 + p2 * q2;
  cs = __builtin_elementwise_min(vf2{1.f, 1.f},
       __builtin_elementwise_max(vf2{-1.f, -1.f}, cs));
  vf2 u0 = q0 - cs * p0;
  vf2 u1 = q1 - cs * p1;
  vf2 u2 = q2 - cs * p2;
  vf2 un2raw = u0 * u0 + u1 * u1 + u2 * u2;  // R5: from components
  vf2 un2 = __builtin_elementwise_max(un2raw, vf2{1e-24f, 1e-24f});
  vf2 ax = __builtin_elementwise_abs(cs);
  vf2 s = __builtin_elementwise_sqrt(vf2{1.f, 1.f} - ax);
  vf2 poly = ((ax * -0.0187293f + 0.0742610f) * ax - 0.2121144f) * ax
             + 1.5707288f;
  vf2 th = s * poly;
  vf2 theta;
  theta.x = (cs.x >= 0.0f) ? th.x : (PI_F - th.x);
  theta.y = (cs.y >= 0.0f) ? th.y : (PI_F - th.y);
  vf2 rsq;
  rsq.x = __builtin_amdgcn_rsqf(un2.x);
  rsq.y = __builtin_amdgcn_rsqf(un2.y);
  vf2 coef = w * theta * rsq;
  bool bx = (un2raw.x < 1e-4f) && (w.x > 0.f);  // fp16 direction-noise regime
  bool by = (un2raw.y < 1e-4f) && (w.y > 0.f);
  if (bx) coef.x = 0.f;
  if (by) coef.y = 0.f;
  a0 += coef * u0;
  a1 += coef * u1;
  a2 += coef * u2;
  if (__builtin_expect(bx, 0)) {
    float d0, d1, d2;
    redo32(xf, vA, c3, p0.x, p1.x, p2.x, w.x, d0, d1, d2);
    a0.x += d0; a1.x += d1; a2.x += d2;
  }
  if (__builtin_expect(by, 0)) {
    float d0, d1, d2;
    redo32(xf, vB, c3, p0.x, p1.x, p2.x, w.y, d0, d1, d2);
    a0.y += d0; a1.y += d1; a2.y += d2;
  }
}

__device__ __forceinline__ void node_step(
    float a0, float a1, float a2, float ws, float p0, float p1, float p2,
    float ts, float dsv, float& y0, float& y1, float& y2) {
  // v_lap = -agg/deg; nrm/scale sign-invariant; -(v_lap*scale)*t = +g*scale*t
  float invdg = __builtin_amdgcn_rcpf(ws + 1e-12f);
  float g0 = a0 * invdg, g1 = a1 * invdg, g2 = a2 * invdg;
  float nrm = sqrtf(fmaf(g0, g0, fmaf(g1, g1, g2 * g2)) + EPS64F);
  float tch = ts * ts * 0.5f;  // t_sqrt^2 / N_STEPS
  float dch = dsv * dsv;
  float alp = __builtin_amdgcn_rcpf(1.0f + __expf(dch - nrm));  // sigmoid
  float scale = (nrm * alp <= 1.0f) ? alp : __builtin_amdgcn_rcpf(nrm);
  float f = scale * tch;
  float v0 = g0 * f, v1 = g1 * f, v2 = g2 * f;
  float nv = sqrtf(fmaf(v0, v0, fmaf(v1, v1, v2 * v2)));
  float cn = __cosf(nv);
  float sc = (nv > 1e-20f) ? (__sinf(nv) * __builtin_amdgcn_rcpf(nv)) : 1.0f;
  float t0 = fmaf(cn, p0, sc * v0);
  float t1 = fmaf(cn, p1, sc * v1);
  float t2 = fmaf(cn, p2, sc * v2);
  float inv = __builtin_amdgcn_rsqf(fmaf(t0, t0, fmaf(t1, t1, t2 * t2)));
  y0 = t0 * inv; y1 = t1 * inv; y2 = t2 * inv;
}

// Wave per node; lane = k*16+c; 16 edges/wave-iter (4 slots x 4-unroll, pk
// pairs). q = one dwordx2 fp16 gather; p + guard from fp32 xf. pair packs
// (w, rcv*64). yh != null: also emit fp16 copy for the next step.
__global__ __launch_bounds__(256) void flowh_kernel(
    const _Float16* __restrict__ xh, const float* __restrict__ xf,
    const int* __restrict__ row_start, const long long* __restrict__ pair,
    const float* __restrict__ tsq, const float* __restrict__ dsq,
    float* __restrict__ yf, _Float16* __restrict__ yh, int N) {
  int node = blockIdx.x * 4 + (threadIdx.x >> 6);
  if (node >= N) return;
  int lane = threadIdx.x & 63;
  int c = lane & 15;
  int k = lane >> 4;
  int c3 = c * 3, c4 = c * 4;
  int beg = row_start[node];
  int end = row_start[node + 1];
  int ip = node * 48 + c3;
  float ps0 = xf[ip], ps1 = xf[ip + 1], ps2 = xf[ip + 2];
  vf2 p0 = {ps0, ps0}, p1 = {ps1, ps1}, p2 = {ps2, ps2};
  vf2 a0 = {0.f, 0.f}, a1 = {0.f, 0.f}, a2 = {0.f, 0.f}, wsv = {0.f, 0.f};
  int iters = (end - beg + 15) >> 4;
  int j = beg + k;
  for (int t = 0; t < iters; ++t, j += 16) {
    long long e0 = __builtin_nontemporal_load(&pair[j]);
    long long e1 = __builtin_nontemporal_load(&pair[j + 4]);
    long long e2 = __builtin_nontemporal_load(&pair[j + 8]);
    long long e3 = __builtin_nontemporal_load(&pair[j + 12]);
    float w0 = (j      < end) ? __int_as_float((int)(e0 >> 32)) : 0.f;
    float w1 = (j + 4  < end) ? __int_as_float((int)(e1 >> 32)) : 0.f;
    float w2 = (j + 8  < end) ? __int_as_float((int)(e2 >> 32)) : 0.f;
    float w3 = (j + 12 < end) ? __int_as_float((int)(e3 >> 32)) : 0.f;
    int v0 = (int)e0, v1 = (int)e1, v2 = (int)e2, v3 = (int)e3;
    vh4 ha = *(const vh4*)(xh + v0 + c4);
    vh4 hb = *(const vh4*)(xh + v1 + c4);
    vh4 hc = *(const vh4*)(xh + v2 + c4);
    vh4 hd = *(const vh4*)(xh + v3 + c4);
    vf2 wA = {w0, w1}, wB = {w2, w3};
    edge_accum_pk_g(p0, p1, p2,
                    vf2{(float)ha.x, (float)hb.x},
                    vf2{(float)ha.y, (float)hb.y},
                    vf2{(float)ha.z, (float)hb.z},
                    wA, v0, v1, c3, xf, a0, a1, a2);
    edge_accum_pk_g(p0, p1, p2,
                    vf2{(float)hc.x, (float)hd.x},
                    vf2{(float)hc.y, (float)hd.y},
                    vf2{(float)hc.z, (float)hd.z},
                    wB, v2, v3, c3, xf, a0, a1, a2);
    wsv += wA + wB;
  }
  float A0 = a0.x + a0.y, A1 = a1.x + a1.y, A2 = a2.x + a2.y;
  float ws = wsv.x + wsv.y;
  A0 += __shfl_xor(A0, 16); A1 += __shfl_xor(A1, 16);
  A2 += __shfl_xor(A2, 16); ws += __shfl_xor(ws, 16);
  A0 += __shfl_xor(A0, 32); A1 += __shfl_xor(A1, 32);
  A2 += __shfl_xor(A2, 32); ws += __shfl_xor(ws, 32);
  if (k == 0) {
    float y0, y1, y2;
    node_step(A0, A1, A2, ws, ps0, ps1, ps2, tsq[c], dsq[c], y0, y1, y2);
    yf[ip] = y0; yf[ip + 1] = y1; yf[ip + 2] = y2;
    if (yh) {
      vh4 h;
      h.x = (_Float16)y0; h.y = (_Float16)y1; h.z = (_Float16)y2;
      h.w = (_Float16)0.f;
      *(vh4*)(yh + (size_t)(node * 16 + c) * 4) = h;
    }
  }
}

static inline size_t al16(size_t x) { return (x + 15) & ~(size_t)15; }

extern "C" void kernel_launch(void* const* d_in, const int* in_sizes, int n_in,
                              void* d_out, int out_size, void* d_ws, size_t ws_size,
                              hipStream_t stream) {
  const float* nodes = (const float*)d_in[0];  // [N,16,3]
  const float* ew    = (const float*)d_in[1];  // [E]
  const float* tsq   = (const float*)d_in[2];  // [16]
  const float* dsq   = (const float*)d_in[3];  // [16]
  const int*   snd   = (const int*)d_in[4];    // [E]
  const int*   rcv   = (const int*)d_in[5];    // [E]
  float* out = (float*)d_out;

  int E = in_sizes[1];
  int N = in_sizes[0] / 48;

  int NS = (N + (1 << SR_BITS) - 1) >> SR_BITS;  // node subranges
  int NC = (E + (1 << CH_BITS) - 1) >> CH_BITS;  // edge chunks

  // workspace (~44MB, < R13's proven-resident ~50MB):
  // row_start | aux | pair[E+32] | partial2 | boff | tot | pos[E] | xh0
  // aliases: xtmp48 (flow1 fp32 out) on partial2 (dead after scan1);
  //          xh1 (flow1 fp16 out) on boff (dead after fill).
  size_t rsB   = al16((size_t)(N + 4) * 4);
  size_t auxB  = 512;
  size_t pairB = al16((size_t)(E + 32) * 8);
  size_t p2B   = al16(((size_t)NS * NC << SR_BITS) * 4);
  size_t boffB = al16((size_t)NC * N * 4);
  size_t totB  = al16((size_t)N * 4);
  size_t posB  = al16((size_t)E);

  char* base = (char*)d_ws;
  int*           row_start = (int*)base;
  int*           btot      = (int*)(base + rsB);
  int*           boffb     = btot + 64;
  long long*     pair      = (long long*)(base + rsB + auxB);
  int*           partial2  = (int*)(base + rsB + auxB + pairB);
  int*           boff      = (int*)(base + rsB + auxB + pairB + p2B);
  int*           tot       = (int*)(base + rsB + auxB + pairB + p2B + boffB);
  unsigned char* pos       = (unsigned char*)(base + rsB + auxB + pairB + p2B + boffB + totB);
  _Float16*      xh0       = (_Float16*)(base + rsB + auxB + pairB + p2B + boffB + totB + posB);
  float*         xtmp      = (float*)partial2;   // fp32 step-1 out
  _Float16*      xh1       = (_Float16*)boff;    // fp16 step-1 out

  int E4  = E >> 2;
  int nb  = (N + 1023) / 1024;
  int nb2 = (N + 255) / 256;
  int fbk = (E4 + 511) / 512;
  int cb  = (N * 16 + 255) / 256;
  int nfb = (N + 3) / 4;

  conv_kernel<<<cb, 256, 0, stream>>>(nodes, xh0, N * 16);
  lhist_kernel<<<dim3(NC, NS), 256, 0, stream>>>(snd, pos, partial2, E, NC);
  scan1_kernel<<<nb2, 256, 0, stream>>>(partial2, boff, tot, N, NC);
  scanA_kernel<<<nb, 1024, 0, stream>>>(tot, row_start, btot, N);
  scanB_kernel<<<1, 64, 0, stream>>>(btot, boffb, row_start, nb, N);
  scanCD_kernel<<<nb2, 256, 0, stream>>>(row_start, boffb, boff, N, NC);
  fill_kernel<<<fbk, 256, 0, stream>>>((const vi4*)snd, (const vi4*)rcv,
                                       (const vf4*)ew, pos, boff, pair,
                                       snd, rcv, ew, N, E);

  // step1: (xh0, nodes) -> (xtmp fp32, xh1 fp16); step2: (xh1, xtmp) -> out
  flowh_kernel<<<nfb, 256, 0, stream>>>(xh0, nodes, row_start, pair,
                                        tsq, dsq, xtmp, xh1, N);
  flowh_kernel<<<nfb, 256, 0, stream>>>(xh1, xtmp, row_start, pair,
                                        tsq, dsq, out, (_Float16*)0, N);
}